// Round 1
// baseline (1813.609 us; speedup 1.0000x reference)
//
#include <hip/hip_runtime.h>
#include <math.h>

typedef short s16x8 __attribute__((ext_vector_type(8)));
typedef float f32x4 __attribute__((ext_vector_type(4)));
typedef unsigned short u16;

#define S_LEN 2048
#define HID_DIM 4096
#define NH_Q 32
#define NKV_H 8
#define DHEAD 128

__device__ __forceinline__ u16 f2bf(float f) {
  unsigned u = __builtin_bit_cast(unsigned, f);
  u += 0x7fffu + ((u >> 16) & 1u);
  return (u16)(u >> 16);
}

// ---------------- RoPE tables: cos/sin [S][64] ----------------
__global__ void rope_table_kernel(const int* __restrict__ positions,
                                  float* __restrict__ cos_t, float* __restrict__ sin_t) {
  int idx = blockIdx.x * 256 + threadIdx.x;
  if (idx >= S_LEN * 64) return;
  int s = idx >> 6, j = idx & 63;
  float pos = (float)positions[s];
  // inv_freq = 10000^(-j/64) = exp(-j * ln(10000)/64)
  float inv = expf(-(float)j * (9.210340371976184f / 64.0f));
  float ang = pos * inv;
  float sv, cv;
  sincosf(ang, &sv, &cv);
  cos_t[idx] = cv;
  sin_t[idx] = sv;
}

// ---------------- GEMM: C[M][N] = A[M][K] * B[N][K]^T ----------------
// EPI: 0 = f32 row-major out (ld=N); 1 = bf16 out to [b][h][s][d]; 2 = RoPE + bf16 out
// ABF16: A operand already bf16 (u16 bits), else f32 (converted while staging)
template<int EPI, bool ABF16>
__global__ __launch_bounds__(256) void gemm_kernel(
    const void* __restrict__ Aptr, const float* __restrict__ Bw,
    void* __restrict__ outp, int M, int N, int K,
    const float* __restrict__ cos_t, const float* __restrict__ sin_t, int Hh) {
  __shared__ u16 As[128][40];  // 128 x 32 bf16, padded to 40 (80B rows: 16B-aligned, 2-way banks)
  __shared__ u16 Bs[128][40];
  const int t = threadIdx.x;
  const int wave = t >> 6, lane = t & 63;
  const int l15 = lane & 15, lhi = lane >> 4;
  const int bm = blockIdx.y * 128, bn = blockIdx.x * 128;

  const f32x4 fz = {0.f, 0.f, 0.f, 0.f};
  f32x4 acc[2][8];
#pragma unroll
  for (int a0 = 0; a0 < 2; ++a0)
#pragma unroll
    for (int b0 = 0; b0 < 8; ++b0) acc[a0][b0] = fz;

  for (int kt = 0; kt < K; kt += 32) {
    __syncthreads();
    // ---- stage A tile (128 x 32) ----
    if (ABF16) {
      const u16* A = (const u16*)Aptr;
#pragma unroll
      for (int p = 0; p < 2; ++p) {
        int idx = p * 256 + t;
        int row = idx >> 2, kc = (idx & 3) * 8;
        *(s16x8*)&As[row][kc] = *(const s16x8*)(A + (size_t)(bm + row) * K + kt + kc);
      }
    } else {
      const float* A = (const float*)Aptr;
#pragma unroll
      for (int p = 0; p < 4; ++p) {
        int idx = p * 256 + t;
        int row = idx >> 3, kc = (idx & 7) * 4;
        float4 f = *(const float4*)(A + (size_t)(bm + row) * K + kt + kc);
        unsigned lo = (unsigned)f2bf(f.x) | ((unsigned)f2bf(f.y) << 16);
        unsigned hi = (unsigned)f2bf(f.z) | ((unsigned)f2bf(f.w) << 16);
        unsigned* dst = (unsigned*)&As[row][kc];
        dst[0] = lo;
        dst[1] = hi;
      }
    }
    // ---- stage B tile (128 x 32) from f32 weights ----
    {
#pragma unroll
      for (int p = 0; p < 4; ++p) {
        int idx = p * 256 + t;
        int row = idx >> 3, kc = (idx & 7) * 4;
        float4 f = *(const float4*)(Bw + (size_t)(bn + row) * K + kt + kc);
        unsigned lo = (unsigned)f2bf(f.x) | ((unsigned)f2bf(f.y) << 16);
        unsigned hi = (unsigned)f2bf(f.z) | ((unsigned)f2bf(f.w) << 16);
        unsigned* dst = (unsigned*)&Bs[row][kc];
        dst[0] = lo;
        dst[1] = hi;
      }
    }
    __syncthreads();
    // ---- MFMA: wave covers 32 rows x 128 cols ----
    s16x8 bfr[8];
#pragma unroll
    for (int nf = 0; nf < 8; ++nf)
      bfr[nf] = *(const s16x8*)&Bs[nf * 16 + l15][lhi * 8];
#pragma unroll
    for (int mf = 0; mf < 2; ++mf) {
      s16x8 a = *(const s16x8*)&As[wave * 32 + mf * 16 + l15][lhi * 8];
#pragma unroll
      for (int nf = 0; nf < 8; ++nf)
        acc[mf][nf] = __builtin_amdgcn_mfma_f32_16x16x32_bf16(a, bfr[nf], acc[mf][nf], 0, 0, 0);
    }
  }

  // ---- epilogue ----
  if (EPI == 0) {
    float* C = (float*)outp;
#pragma unroll
    for (int mf = 0; mf < 2; ++mf)
#pragma unroll
      for (int nf = 0; nf < 8; ++nf) {
        int col = bn + nf * 16 + l15;
        int rb = bm + wave * 32 + mf * 16 + lhi * 4;
#pragma unroll
        for (int i = 0; i < 4; ++i) C[(size_t)(rb + i) * N + col] = acc[mf][nf][i];
      }
  } else if (EPI == 1) {
    u16* O = (u16*)outp;
#pragma unroll
    for (int mf = 0; mf < 2; ++mf)
#pragma unroll
      for (int nf = 0; nf < 8; ++nf) {
        int col = bn + nf * 16 + l15;
        int h = col >> 7, d = col & 127;
        int rb = bm + wave * 32 + mf * 16 + lhi * 4;
#pragma unroll
        for (int i = 0; i < 4; ++i) {
          int m = rb + i;
          int b = m >> 11, srow = m & 2047;
          O[((size_t)(b * Hh + h) * S_LEN + srow) * DHEAD + d] = f2bf(acc[mf][nf][i]);
        }
      }
  } else {  // EPI == 2: RoPE
    u16* O = (u16*)outp;
    int h = bn >> 7;  // BN=128 == head dim, so block column == one head
#pragma unroll
    for (int mf = 0; mf < 2; ++mf)
#pragma unroll
      for (int nf = 0; nf < 4; ++nf) {
        int j = nf * 16 + l15;  // 0..63
        int rb = bm + wave * 32 + mf * 16 + lhi * 4;
#pragma unroll
        for (int i = 0; i < 4; ++i) {
          int m = rb + i;
          int b = m >> 11, srow = m & 2047;
          float c = cos_t[srow * 64 + j];
          float s = sin_t[srow * 64 + j];
          float x0 = acc[mf][nf][i];
          float x1 = acc[mf][nf + 4][i];
          size_t base = ((size_t)(b * Hh + h) * S_LEN + srow) * DHEAD;
          O[base + j] = f2bf(x0 * c - x1 * s);
          O[base + j + 64] = f2bf(x0 * s + x1 * c);
        }
      }
  }
}

// ---------------- Flash attention (causal, GQA) ----------------
// grid: (S/64, NH, B); 4 waves, each wave owns 16 q rows; KV tile = 64
__global__ __launch_bounds__(256) void attn_kernel(
    const u16* __restrict__ q, const u16* __restrict__ k, const u16* __restrict__ v,
    u16* __restrict__ ctx) {
  __shared__ u16 Qs[64][136];   // padded: 272B rows (16B-aligned, 2-way banks)
  __shared__ u16 Ks[64][136];
  __shared__ u16 Vts[128][72];  // V transposed: [d][kv], 144B rows
  __shared__ u16 Ps[4][16][72]; // per-wave P tile [qrow][kv]

  const int t = threadIdx.x;
  const int wave = t >> 6, lane = t & 63;
  const int l15 = lane & 15, lhi = lane >> 4;
  const int qtile = blockIdx.x, h = blockIdx.y, b = blockIdx.z;
  const int kvh = h >> 2;  // GROUPS = 4

  const u16* qb = q + (((size_t)(b * NH_Q + h)) * S_LEN + qtile * 64) * DHEAD;
  const u16* kb = k + ((size_t)(b * NKV_H + kvh)) * S_LEN * DHEAD;
  const u16* vb = v + ((size_t)(b * NKV_H + kvh)) * S_LEN * DHEAD;

  // stage Q (64 x 128)
#pragma unroll
  for (int p = 0; p < 4; ++p) {
    int idx = p * 256 + t;
    int row = idx >> 4, d0 = (idx & 15) * 8;
    *(s16x8*)&Qs[row][d0] = *(const s16x8*)(qb + row * DHEAD + d0);
  }

  const f32x4 fz = {0.f, 0.f, 0.f, 0.f};
  f32x4 acc[8];
#pragma unroll
  for (int i = 0; i < 8; ++i) acc[i] = fz;
  float mrow[4] = {-INFINITY, -INFINITY, -INFINITY, -INFINITY};
  float lsum[4] = {0.f, 0.f, 0.f, 0.f};

  const float scale = 0.08838834764831845f;  // 1/sqrt(128)
  const int ntiles = qtile + 1;

  for (int tt = 0; tt < ntiles; ++tt) {
    __syncthreads();  // protect K/V LDS from previous iteration's readers
    // stage K (row-major) and V (transposed)
#pragma unroll
    for (int p = 0; p < 4; ++p) {
      int idx = p * 256 + t;
      int row = idx >> 4, d0 = (idx & 15) * 8;
      *(s16x8*)&Ks[row][d0] = *(const s16x8*)(kb + (size_t)(tt * 64 + row) * DHEAD + d0);
      s16x8 vv = *(const s16x8*)(vb + (size_t)(tt * 64 + row) * DHEAD + d0);
#pragma unroll
      for (int j = 0; j < 8; ++j) Vts[d0 + j][row] = (u16)vv[j];
    }
    __syncthreads();

    // ---- S = Q K^T (wave: 16 q rows x 64 kv) ----
    f32x4 sacc[4];
#pragma unroll
    for (int i = 0; i < 4; ++i) sacc[i] = fz;
    const int qlo = wave * 16;
#pragma unroll
    for (int ks = 0; ks < 4; ++ks) {
      s16x8 a = *(const s16x8*)&Qs[qlo + l15][ks * 32 + lhi * 8];
#pragma unroll
      for (int nf = 0; nf < 4; ++nf) {
        s16x8 bb = *(const s16x8*)&Ks[nf * 16 + l15][ks * 32 + lhi * 8];
        sacc[nf] = __builtin_amdgcn_mfma_f32_16x16x32_bf16(a, bb, sacc[nf], 0, 0, 0);
      }
    }

    // ---- scale + causal mask + online softmax ----
    const int qr_base = qtile * 64 + qlo + lhi * 4;
    const int kc_base = tt * 64;
    float pmax[4] = {-INFINITY, -INFINITY, -INFINITY, -INFINITY};
#pragma unroll
    for (int nf = 0; nf < 4; ++nf) {
      int kc = kc_base + nf * 16 + l15;
#pragma unroll
      for (int i = 0; i < 4; ++i) {
        float sv = sacc[nf][i] * scale;
        sv = (kc <= qr_base + i) ? sv : -INFINITY;
        sacc[nf][i] = sv;
        pmax[i] = fmaxf(pmax[i], sv);
      }
    }
#pragma unroll
    for (int i = 0; i < 4; ++i) {
      pmax[i] = fmaxf(pmax[i], __shfl_xor(pmax[i], 1, 64));
      pmax[i] = fmaxf(pmax[i], __shfl_xor(pmax[i], 2, 64));
      pmax[i] = fmaxf(pmax[i], __shfl_xor(pmax[i], 4, 64));
      pmax[i] = fmaxf(pmax[i], __shfl_xor(pmax[i], 8, 64));
    }
    float alpha[4];
#pragma unroll
    for (int i = 0; i < 4; ++i) {
      float mn = fmaxf(mrow[i], pmax[i]);
      alpha[i] = __expf(mrow[i] - mn);
      mrow[i] = mn;
    }
    float rsum[4] = {0.f, 0.f, 0.f, 0.f};
#pragma unroll
    for (int nf = 0; nf < 4; ++nf)
#pragma unroll
      for (int i = 0; i < 4; ++i) {
        float pv = __expf(sacc[nf][i] - mrow[i]);
        sacc[nf][i] = pv;
        rsum[i] += pv;
      }
#pragma unroll
    for (int i = 0; i < 4; ++i) {
      rsum[i] += __shfl_xor(rsum[i], 1, 64);
      rsum[i] += __shfl_xor(rsum[i], 2, 64);
      rsum[i] += __shfl_xor(rsum[i], 4, 64);
      rsum[i] += __shfl_xor(rsum[i], 8, 64);
      lsum[i] = lsum[i] * alpha[i] + rsum[i];
    }
#pragma unroll
    for (int df = 0; df < 8; ++df)
#pragma unroll
      for (int i = 0; i < 4; ++i) acc[df][i] *= alpha[i];

    // ---- P -> LDS (C-layout write, A-layout read; per-wave buffer) ----
#pragma unroll
    for (int nf = 0; nf < 4; ++nf)
#pragma unroll
      for (int i = 0; i < 4; ++i)
        Ps[wave][lhi * 4 + i][nf * 16 + l15] = f2bf(sacc[nf][i]);

    // ---- ctx += P V ----
#pragma unroll
    for (int ks = 0; ks < 2; ++ks) {
      s16x8 a = *(const s16x8*)&Ps[wave][l15][ks * 32 + lhi * 8];
#pragma unroll
      for (int df = 0; df < 8; ++df) {
        s16x8 bb = *(const s16x8*)&Vts[df * 16 + l15][ks * 32 + lhi * 8];
        acc[df] = __builtin_amdgcn_mfma_f32_16x16x32_bf16(a, bb, acc[df], 0, 0, 0);
      }
    }
  }

  // ---- epilogue: ctx[b][s][h*128+d] bf16 ----
#pragma unroll
  for (int i = 0; i < 4; ++i) {
    float rl = 1.0f / lsum[i];
    int m = b * S_LEN + qtile * 64 + wave * 16 + lhi * 4 + i;
#pragma unroll
    for (int df = 0; df < 8; ++df) {
      int col = h * DHEAD + df * 16 + l15;
      ctx[(size_t)m * (NH_Q * DHEAD) + col] = f2bf(acc[df][i] * rl);
    }
  }
}

extern "C" void kernel_launch(void* const* d_in, const int* in_sizes, int n_in,
                              void* d_out, int out_size, void* d_ws, size_t ws_size,
                              hipStream_t stream) {
  const float* x = (const float*)d_in[0];
  const int* positions = (const int*)d_in[1];
  const float* wq = (const float*)d_in[2];
  const float* wk = (const float*)d_in[3];
  const float* wv = (const float*)d_in[4];
  const float* wo = (const float*)d_in[5];
  float* out = (float*)d_out;

  char* ws = (char*)d_ws;
  float* cos_t = (float*)ws;                               // 2048*64*4 = 512 KB
  float* sin_t = (float*)(ws + 524288);                    // 512 KB
  u16* q_ws = (u16*)(ws + 1048576);                        // 32 MB
  u16* k_ws = (u16*)(ws + 1048576 + 33554432);             // 8 MB
  u16* v_ws = (u16*)(ws + 1048576 + 33554432 + 8388608);   // 8 MB
  u16* ctx_ws = (u16*)(ws + 1048576 + 33554432 + 2 * 8388608);  // 32 MB

  rope_table_kernel<<<512, 256, 0, stream>>>(positions, cos_t, sin_t);
  // q = rope(x @ wq^T): M=4096, N=4096
  gemm_kernel<2, false><<<dim3(32, 32), 256, 0, stream>>>(
      x, wq, q_ws, 4096, 4096, 4096, cos_t, sin_t, NH_Q);
  // k = rope(x @ wk^T): N=1024
  gemm_kernel<2, false><<<dim3(8, 32), 256, 0, stream>>>(
      x, wk, k_ws, 4096, 1024, 4096, cos_t, sin_t, NKV_H);
  // v = x @ wv^T
  gemm_kernel<1, false><<<dim3(8, 32), 256, 0, stream>>>(
      x, wv, v_ws, 4096, 1024, 4096, nullptr, nullptr, NKV_H);
  // attention
  attn_kernel<<<dim3(32, 32, 2), 256, 0, stream>>>(q_ws, k_ws, v_ws, ctx_ws);
  // out = ctx @ wo^T (f32 out)
  gemm_kernel<0, true><<<dim3(32, 32), 256, 0, stream>>>(
      ctx_ws, wo, out, 4096, 4096, 4096, nullptr, nullptr, 0);
}

// Round 2
// 910.344 us; speedup vs baseline: 1.9922x; 1.9922x over previous
//
#include <hip/hip_runtime.h>
#include <math.h>

typedef short s16x8 __attribute__((ext_vector_type(8)));
typedef float f32x4 __attribute__((ext_vector_type(4)));
typedef unsigned short u16;

#define S_LEN 2048
#define HID_DIM 4096
#define NH_Q 32
#define NKV_H 8
#define DHEAD 128

__device__ __forceinline__ u16 f2bf(float f) {
  unsigned u = __builtin_bit_cast(unsigned, f);
  u += 0x7fffu + ((u >> 16) & 1u);
  return (u16)(u >> 16);
}

// ---------------- f32 -> bf16 bulk convert ----------------
__global__ void cvt_kernel(const float* __restrict__ in, u16* __restrict__ out, int n4) {
  int stride = gridDim.x * blockDim.x;
  for (int i = blockIdx.x * blockDim.x + threadIdx.x; i < n4; i += stride) {
    float4 f = ((const float4*)in)[i];
    uint2 o;
    o.x = (unsigned)f2bf(f.x) | ((unsigned)f2bf(f.y) << 16);
    o.y = (unsigned)f2bf(f.z) | ((unsigned)f2bf(f.w) << 16);
    ((uint2*)out)[i] = o;
  }
}

// ---------------- RoPE tables: cos/sin [S][64] ----------------
__global__ void rope_table_kernel(const int* __restrict__ positions,
                                  float* __restrict__ cos_t, float* __restrict__ sin_t) {
  int idx = blockIdx.x * 256 + threadIdx.x;
  if (idx >= S_LEN * 64) return;
  int s = idx >> 6, j = idx & 63;
  float pos = (float)positions[s];
  float inv = expf(-(float)j * (9.210340371976184f / 64.0f));
  float ang = pos * inv;
  float sv, cv;
  sincosf(ang, &sv, &cv);
  cos_t[idx] = cv;
  sin_t[idx] = sv;
}

// ---------------- GEMM: C[M][N] = A[M][K] * B[N][K]^T, BK=64 ----------------
// EPI: 0 = f32 row-major out; 1 = bf16 out to [b][h][s][d]; 2 = RoPE + bf16 out
template<int EPI, bool ABF16, bool BBF16>
__global__ __launch_bounds__(256) void gemm_kernel(
    const void* __restrict__ Aptr, const void* __restrict__ Bptr,
    void* __restrict__ outp, int M, int N, int K,
    const float* __restrict__ cos_t, const float* __restrict__ sin_t, int Hh) {
  __shared__ u16 As[128][72];  // 128 x 64 bf16, stride 144B (36 dw === 4 mod 32: even spread)
  __shared__ u16 Bs[128][72];
  const int t = threadIdx.x;
  const int wave = t >> 6, lane = t & 63;
  const int l15 = lane & 15, lhi = lane >> 4;
  const int bm = blockIdx.y * 128, bn = blockIdx.x * 128;

  const f32x4 fz = {0.f, 0.f, 0.f, 0.f};
  f32x4 acc[2][8];
#pragma unroll
  for (int a0 = 0; a0 < 2; ++a0)
#pragma unroll
    for (int b0 = 0; b0 < 8; ++b0) acc[a0][b0] = fz;

  for (int kt = 0; kt < K; kt += 64) {
    __syncthreads();
    // ---- stage A tile (128 x 64) ----
    if (ABF16) {
      const u16* A = (const u16*)Aptr;
#pragma unroll
      for (int p = 0; p < 4; ++p) {
        int row = p * 32 + (t >> 3), kc = (t & 7) * 8;
        *(s16x8*)&As[row][kc] = *(const s16x8*)(A + (size_t)(bm + row) * K + kt + kc);
      }
    } else {
      const float* A = (const float*)Aptr;
#pragma unroll
      for (int p = 0; p < 8; ++p) {
        int row = p * 16 + (t >> 4), kc = (t & 15) * 4;
        float4 f = *(const float4*)(A + (size_t)(bm + row) * K + kt + kc);
        unsigned* dst = (unsigned*)&As[row][kc];
        dst[0] = (unsigned)f2bf(f.x) | ((unsigned)f2bf(f.y) << 16);
        dst[1] = (unsigned)f2bf(f.z) | ((unsigned)f2bf(f.w) << 16);
      }
    }
    // ---- stage B tile (128 x 64) ----
    if (BBF16) {
      const u16* Bw = (const u16*)Bptr;
#pragma unroll
      for (int p = 0; p < 4; ++p) {
        int row = p * 32 + (t >> 3), kc = (t & 7) * 8;
        *(s16x8*)&Bs[row][kc] = *(const s16x8*)(Bw + (size_t)(bn + row) * K + kt + kc);
      }
    } else {
      const float* Bw = (const float*)Bptr;
#pragma unroll
      for (int p = 0; p < 8; ++p) {
        int row = p * 16 + (t >> 4), kc = (t & 15) * 4;
        float4 f = *(const float4*)(Bw + (size_t)(bn + row) * K + kt + kc);
        unsigned* dst = (unsigned*)&Bs[row][kc];
        dst[0] = (unsigned)f2bf(f.x) | ((unsigned)f2bf(f.y) << 16);
        dst[1] = (unsigned)f2bf(f.z) | ((unsigned)f2bf(f.w) << 16);
      }
    }
    __syncthreads();
    // ---- MFMA: wave covers 32 rows x 128 cols, two K=32 steps ----
#pragma unroll
    for (int ks = 0; ks < 2; ++ks) {
      s16x8 bfr[8];
#pragma unroll
      for (int nf = 0; nf < 8; ++nf)
        bfr[nf] = *(const s16x8*)&Bs[nf * 16 + l15][ks * 32 + lhi * 8];
#pragma unroll
      for (int mf = 0; mf < 2; ++mf) {
        s16x8 a = *(const s16x8*)&As[wave * 32 + mf * 16 + l15][ks * 32 + lhi * 8];
#pragma unroll
        for (int nf = 0; nf < 8; ++nf)
          acc[mf][nf] = __builtin_amdgcn_mfma_f32_16x16x32_bf16(a, bfr[nf], acc[mf][nf], 0, 0, 0);
      }
    }
  }

  // ---- epilogue ----
  if (EPI == 0) {
    float* C = (float*)outp;
#pragma unroll
    for (int mf = 0; mf < 2; ++mf)
#pragma unroll
      for (int nf = 0; nf < 8; ++nf) {
        int col = bn + nf * 16 + l15;
        int rb = bm + wave * 32 + mf * 16 + lhi * 4;
#pragma unroll
        for (int i = 0; i < 4; ++i) C[(size_t)(rb + i) * N + col] = acc[mf][nf][i];
      }
  } else if (EPI == 1) {
    u16* O = (u16*)outp;
#pragma unroll
    for (int mf = 0; mf < 2; ++mf)
#pragma unroll
      for (int nf = 0; nf < 8; ++nf) {
        int col = bn + nf * 16 + l15;
        int h = col >> 7, d = col & 127;
        int rb = bm + wave * 32 + mf * 16 + lhi * 4;
#pragma unroll
        for (int i = 0; i < 4; ++i) {
          int m = rb + i;
          int b = m >> 11, srow = m & 2047;
          O[((size_t)(b * Hh + h) * S_LEN + srow) * DHEAD + d] = f2bf(acc[mf][nf][i]);
        }
      }
  } else {  // EPI == 2: RoPE
    u16* O = (u16*)outp;
    int h = bn >> 7;
#pragma unroll
    for (int mf = 0; mf < 2; ++mf)
#pragma unroll
      for (int nf = 0; nf < 4; ++nf) {
        int j = nf * 16 + l15;
        int rb = bm + wave * 32 + mf * 16 + lhi * 4;
#pragma unroll
        for (int i = 0; i < 4; ++i) {
          int m = rb + i;
          int b = m >> 11, srow = m & 2047;
          float c = cos_t[srow * 64 + j];
          float s = sin_t[srow * 64 + j];
          float x0 = acc[mf][nf][i];
          float x1 = acc[mf][nf + 4][i];
          size_t base = ((size_t)(b * Hh + h) * S_LEN + srow) * DHEAD;
          O[base + j] = f2bf(x0 * c - x1 * s);
          O[base + j + 64] = f2bf(x0 * s + x1 * c);
        }
      }
  }
}

// ---------------- Flash attention (causal, GQA) ----------------
// grid: (S/128, NH, B); 8 waves, each wave owns 16 q rows (Q in registers); KV tile = 64
__global__ __launch_bounds__(512) void attn_kernel(
    const u16* __restrict__ q, const u16* __restrict__ k, const u16* __restrict__ v,
    u16* __restrict__ ctx) {
  __shared__ u16 Ks[64][136];    // K row-major [kv][d], stride 272B
  __shared__ u16 Vts[128][72];   // V transposed [d][kv], kv-block XOR-swizzled
  __shared__ u16 Ps[8][16][72];  // per-wave P tile [qrow][kv]

  const int t = threadIdx.x;
  const int wave = t >> 6, lane = t & 63;
  const int l15 = lane & 15, lhi = lane >> 4;
  const int qtile = gridDim.x - 1 - blockIdx.x;  // heavy blocks dispatch first
  const int h = blockIdx.y, b = blockIdx.z;
  const int kvh = h >> 2;  // GROUPS = 4

  const u16* qb = q + (((size_t)(b * NH_Q + h)) * S_LEN + qtile * 128) * DHEAD;
  const u16* kb = k + ((size_t)(b * NKV_H + kvh)) * S_LEN * DHEAD;
  const u16* vb = v + ((size_t)(b * NKV_H + kvh)) * S_LEN * DHEAD;

  // Q fragments in registers (wave's 16 rows x 128 cols)
  s16x8 qf[4];
#pragma unroll
  for (int ks = 0; ks < 4; ++ks)
    qf[ks] = *(const s16x8*)(qb + (size_t)(wave * 16 + l15) * DHEAD + ks * 32 + lhi * 8);

  const f32x4 fz = {0.f, 0.f, 0.f, 0.f};
  f32x4 acc[8];
#pragma unroll
  for (int i = 0; i < 8; ++i) acc[i] = fz;
  float mrow[4] = {-INFINITY, -INFINITY, -INFINITY, -INFINITY};
  float lsum[4] = {0.f, 0.f, 0.f, 0.f};

  const float scale = 0.08838834764831845f;  // 1/sqrt(128)
  const int ntiles = qtile * 2 + 2;
  const int wrow_min = qtile * 128 + wave * 16;

  // staging regs: 2 passes x 8 elems (512 threads cover 64x128 in 2 passes)
  const int srow = t >> 4, sd0 = (t & 15) * 8;  // pass 0: rows 0..31; pass 1: rows 32..63
  s16x8 kreg[2], vreg[2];
#pragma unroll
  for (int p = 0; p < 2; ++p) {
    int row = p * 32 + srow;
    kreg[p] = *(const s16x8*)(kb + (size_t)row * DHEAD + sd0);
    vreg[p] = *(const s16x8*)(vb + (size_t)row * DHEAD + sd0);
  }

  for (int tt = 0; tt < ntiles; ++tt) {
    __syncthreads();  // previous tile's readers done
    // ---- write staged K/V regs to LDS ----
    {
      const int sw = (sd0 >> 3) & 7;
#pragma unroll
      for (int p = 0; p < 2; ++p) {
        int row = p * 32 + srow;
        *(s16x8*)&Ks[row][sd0] = kreg[p];
        int colb = (((row >> 3) ^ sw) << 3) + (row & 7);
#pragma unroll
        for (int j = 0; j < 8; ++j) Vts[sd0 + j][colb] = (u16)vreg[p][j];
      }
    }
    __syncthreads();
    // ---- prefetch next tile into regs (overlaps with compute below) ----
    if (tt + 1 < ntiles) {
#pragma unroll
      for (int p = 0; p < 2; ++p) {
        int row = (tt + 1) * 64 + p * 32 + srow;
        kreg[p] = *(const s16x8*)(kb + (size_t)row * DHEAD + sd0);
        vreg[p] = *(const s16x8*)(vb + (size_t)row * DHEAD + sd0);
      }
    }

    const int kc_base = tt * 64;
    if (kc_base <= wrow_min + 15) {  // wave-uniform: skip fully-masked tiles
      // ---- S = Q K^T (wave: 16 q rows x 64 kv) ----
      f32x4 sacc[4];
#pragma unroll
      for (int i = 0; i < 4; ++i) sacc[i] = fz;
      __builtin_amdgcn_s_setprio(1);
#pragma unroll
      for (int ks = 0; ks < 4; ++ks) {
#pragma unroll
        for (int nf = 0; nf < 4; ++nf) {
          s16x8 bb = *(const s16x8*)&Ks[nf * 16 + l15][ks * 32 + lhi * 8];
          sacc[nf] = __builtin_amdgcn_mfma_f32_16x16x32_bf16(qf[ks], bb, sacc[nf], 0, 0, 0);
        }
      }
      __builtin_amdgcn_s_setprio(0);

      // ---- scale + causal mask + online softmax ----
      const int qr_base = wrow_min + lhi * 4;
      float pmax[4] = {-INFINITY, -INFINITY, -INFINITY, -INFINITY};
      if (kc_base + 63 > wrow_min) {  // diagonal tile: mask needed
#pragma unroll
        for (int nf = 0; nf < 4; ++nf) {
          int kc = kc_base + nf * 16 + l15;
#pragma unroll
          for (int i = 0; i < 4; ++i) {
            float sv = sacc[nf][i] * scale;
            sv = (kc <= qr_base + i) ? sv : -INFINITY;
            sacc[nf][i] = sv;
            pmax[i] = fmaxf(pmax[i], sv);
          }
        }
      } else {
#pragma unroll
        for (int nf = 0; nf < 4; ++nf)
#pragma unroll
          for (int i = 0; i < 4; ++i) {
            float sv = sacc[nf][i] * scale;
            sacc[nf][i] = sv;
            pmax[i] = fmaxf(pmax[i], sv);
          }
      }
#pragma unroll
      for (int i = 0; i < 4; ++i) {
        pmax[i] = fmaxf(pmax[i], __shfl_xor(pmax[i], 1, 64));
        pmax[i] = fmaxf(pmax[i], __shfl_xor(pmax[i], 2, 64));
        pmax[i] = fmaxf(pmax[i], __shfl_xor(pmax[i], 4, 64));
        pmax[i] = fmaxf(pmax[i], __shfl_xor(pmax[i], 8, 64));
      }
      float alpha[4];
#pragma unroll
      for (int i = 0; i < 4; ++i) {
        float mn = fmaxf(mrow[i], pmax[i]);
        alpha[i] = __expf(mrow[i] - mn);
        mrow[i] = mn;
      }
      float rsum[4] = {0.f, 0.f, 0.f, 0.f};
#pragma unroll
      for (int nf = 0; nf < 4; ++nf)
#pragma unroll
        for (int i = 0; i < 4; ++i) {
          float pv = __expf(sacc[nf][i] - mrow[i]);
          sacc[nf][i] = pv;
          rsum[i] += pv;
        }
#pragma unroll
      for (int i = 0; i < 4; ++i) {
        rsum[i] += __shfl_xor(rsum[i], 1, 64);
        rsum[i] += __shfl_xor(rsum[i], 2, 64);
        rsum[i] += __shfl_xor(rsum[i], 4, 64);
        rsum[i] += __shfl_xor(rsum[i], 8, 64);
        lsum[i] = lsum[i] * alpha[i] + rsum[i];
      }
#pragma unroll
      for (int df = 0; df < 8; ++df)
#pragma unroll
        for (int i = 0; i < 4; ++i) acc[df][i] *= alpha[i];

      // ---- P -> per-wave LDS (C-layout write, A-layout read) ----
#pragma unroll
      for (int nf = 0; nf < 4; ++nf)
#pragma unroll
        for (int i = 0; i < 4; ++i)
          Ps[wave][lhi * 4 + i][nf * 16 + l15] = f2bf(sacc[nf][i]);

      // ---- ctx += P V ----
      __builtin_amdgcn_s_setprio(1);
#pragma unroll
      for (int ks = 0; ks < 2; ++ks) {
        s16x8 a = *(const s16x8*)&Ps[wave][l15][ks * 32 + lhi * 8];
#pragma unroll
        for (int df = 0; df < 8; ++df) {
          int d = df * 16 + l15;
          s16x8 bb = *(const s16x8*)&Vts[d][(((ks * 4 + lhi) ^ ((d >> 3) & 7)) << 3)];
          acc[df] = __builtin_amdgcn_mfma_f32_16x16x32_bf16(a, bb, acc[df], 0, 0, 0);
        }
      }
      __builtin_amdgcn_s_setprio(0);
    }
  }

  // ---- epilogue: ctx[b][s][h*128+d] bf16 ----
#pragma unroll
  for (int i = 0; i < 4; ++i) {
    float rl = 1.0f / lsum[i];
    int m = b * S_LEN + qtile * 128 + wave * 16 + lhi * 4 + i;
#pragma unroll
    for (int df = 0; df < 8; ++df) {
      int col = h * DHEAD + df * 16 + l15;
      ctx[(size_t)m * (NH_Q * DHEAD) + col] = f2bf(acc[df][i] * rl);
    }
  }
}

extern "C" void kernel_launch(void* const* d_in, const int* in_sizes, int n_in,
                              void* d_out, int out_size, void* d_ws, size_t ws_size,
                              hipStream_t stream) {
  const float* x = (const float*)d_in[0];
  const int* positions = (const int*)d_in[1];
  const float* wq = (const float*)d_in[2];
  const float* wk = (const float*)d_in[3];
  const float* wv = (const float*)d_in[4];
  const float* wo = (const float*)d_in[5];
  float* out = (float*)d_out;

  char* ws = (char*)d_ws;
  const size_t MB1 = 1048576;
  const size_t SZ_X = 33554432;   // 2*2048*4096 bf16
  const size_t SZ_WQ = 33554432;  // 4096*4096 bf16
  const size_t SZ_WK = 8388608;   // 1024*4096 bf16
  const size_t NEED_FULL = MB1 + SZ_X + SZ_WQ + 2 * SZ_WK  // x_bf, w_bf, wk_bf, wv_bf
                         + SZ_WQ + 2 * SZ_WK;              // q, k, v   (ctx overlays x_bf)

  float* cos_t = (float*)ws;
  float* sin_t = (float*)(ws + MB1 / 2);

  rope_table_kernel<<<512, 256, 0, stream>>>(positions, cos_t, sin_t);

  if (ws_size >= NEED_FULL) {
    // -------- full plan: pre-convert everything to bf16 --------
    char* p = ws + MB1;
    u16* x_bf = (u16*)p;            p += SZ_X;    // later reused as ctx
    u16* w_bf = (u16*)p;            p += SZ_WQ;   // wq first, wo later
    u16* wk_bf = (u16*)p;           p += SZ_WK;
    u16* wv_bf = (u16*)p;           p += SZ_WK;
    u16* q_ws = (u16*)p;            p += SZ_WQ;
    u16* k_ws = (u16*)p;            p += SZ_WK;
    u16* v_ws = (u16*)p;            p += SZ_WK;
    u16* ctx_ws = x_bf;

    cvt_kernel<<<2048, 256, 0, stream>>>(x, x_bf, 16777216 / 4);
    cvt_kernel<<<2048, 256, 0, stream>>>(wq, w_bf, 16777216 / 4);
    cvt_kernel<<<1024, 256, 0, stream>>>(wk, wk_bf, 4194304 / 4);
    cvt_kernel<<<1024, 256, 0, stream>>>(wv, wv_bf, 4194304 / 4);

    gemm_kernel<2, true, true><<<dim3(32, 32), 256, 0, stream>>>(
        x_bf, w_bf, q_ws, 4096, 4096, 4096, cos_t, sin_t, NH_Q);
    cvt_kernel<<<2048, 256, 0, stream>>>(wo, w_bf, 16777216 / 4);  // w_bf now = wo_bf
    gemm_kernel<2, true, true><<<dim3(8, 32), 256, 0, stream>>>(
        x_bf, wk_bf, k_ws, 4096, 1024, 4096, cos_t, sin_t, NKV_H);
    gemm_kernel<1, true, true><<<dim3(8, 32), 256, 0, stream>>>(
        x_bf, wv_bf, v_ws, 4096, 1024, 4096, nullptr, nullptr, NKV_H);
    attn_kernel<<<dim3(16, 32, 2), 512, 0, stream>>>(q_ws, k_ws, v_ws, ctx_ws);
    gemm_kernel<0, true, true><<<dim3(32, 32), 256, 0, stream>>>(
        ctx_ws, w_bf, out, 4096, 4096, 4096, nullptr, nullptr, 0);
  } else {
    // -------- fallback: stage-time conversion (81 MB ws) --------
    u16* q_ws = (u16*)(ws + MB1);
    u16* k_ws = (u16*)(ws + MB1 + SZ_WQ);
    u16* v_ws = (u16*)(ws + MB1 + SZ_WQ + SZ_WK);
    u16* ctx_ws = (u16*)(ws + MB1 + SZ_WQ + 2 * SZ_WK);

    gemm_kernel<2, false, false><<<dim3(32, 32), 256, 0, stream>>>(
        x, wq, q_ws, 4096, 4096, 4096, cos_t, sin_t, NH_Q);
    gemm_kernel<2, false, false><<<dim3(8, 32), 256, 0, stream>>>(
        x, wk, k_ws, 4096, 1024, 4096, cos_t, sin_t, NKV_H);
    gemm_kernel<1, false, false><<<dim3(8, 32), 256, 0, stream>>>(
        x, wv, v_ws, 4096, 1024, 4096, nullptr, nullptr, NKV_H);
    attn_kernel<<<dim3(16, 32, 2), 512, 0, stream>>>(q_ws, k_ws, v_ws, ctx_ws);
    gemm_kernel<0, true, false><<<dim3(32, 32), 256, 0, stream>>>(
        ctx_ws, wo, out, 4096, 4096, 4096, nullptr, nullptr, 0);
  }
}

// Round 3
// 792.034 us; speedup vs baseline: 2.2898x; 1.1494x over previous
//
#include <hip/hip_runtime.h>
#include <math.h>

typedef short s16x8 __attribute__((ext_vector_type(8)));
typedef float f32x4 __attribute__((ext_vector_type(4)));
typedef unsigned u32x4 __attribute__((ext_vector_type(4)));
typedef unsigned short u16;

#define S_LEN 2048
#define HID_DIM 4096
#define NH_Q 32
#define NKV_H 8
#define DHEAD 128

__device__ __forceinline__ u16 f2bf(float f) {
  unsigned u = __builtin_bit_cast(unsigned, f);
  u += 0x7fffu + ((u >> 16) & 1u);
  return (u16)(u >> 16);
}

// ---------------- f32 -> bf16 bulk convert ----------------
__global__ void cvt_kernel(const float* __restrict__ in, u16* __restrict__ out, int n4) {
  int stride = gridDim.x * blockDim.x;
  for (int i = blockIdx.x * blockDim.x + threadIdx.x; i < n4; i += stride) {
    float4 f = ((const float4*)in)[i];
    uint2 o;
    o.x = (unsigned)f2bf(f.x) | ((unsigned)f2bf(f.y) << 16);
    o.y = (unsigned)f2bf(f.z) | ((unsigned)f2bf(f.w) << 16);
    ((uint2*)out)[i] = o;
  }
}

// ---------------- RoPE tables: cos/sin [S][64] ----------------
__global__ void rope_table_kernel(const int* __restrict__ positions,
                                  float* __restrict__ cos_t, float* __restrict__ sin_t) {
  int idx = blockIdx.x * 256 + threadIdx.x;
  if (idx >= S_LEN * 64) return;
  int s = idx >> 6, j = idx & 63;
  float pos = (float)positions[s];
  float inv = expf(-(float)j * (9.210340371976184f / 64.0f));
  float ang = pos * inv;
  float sv, cv;
  sincosf(ang, &sv, &cv);
  cos_t[idx] = cv;
  sin_t[idx] = sv;
}

// ---------------- GEMM: C[M][N] = A[M][K] * B[N][K]^T, BK=64 ----------------
// EPI: 0 = f32 row-major out; 1 = bf16 out to [b][h][s][d]; 2 = RoPE + bf16 out;
//      3 = fused kv: cols [0,1024) RoPE->outp (k), cols [1024,2048) plain->outp2 (v)
template<int EPI, bool ABF16, bool BBF16>
__global__ __launch_bounds__(256) void gemm_kernel(
    const void* __restrict__ Aptr, const void* __restrict__ Bptr,
    void* __restrict__ outp, void* __restrict__ outp2, int M, int N, int K,
    const float* __restrict__ cos_t, const float* __restrict__ sin_t, int Hh) {
  __shared__ u16 As[128][72];  // 128 x 64 bf16, stride 144B
  __shared__ u16 Bs[128][72];
  const int t = threadIdx.x;
  const int wave = t >> 6, lane = t & 63;
  const int l15 = lane & 15, lhi = lane >> 4;
  // bijective XCD swizzle (all our grids are multiples of 8)
  const int gx = gridDim.x;
  const int nwg = gx * gridDim.y;
  const int id = blockIdx.y * gx + blockIdx.x;
  const int swz = (id & 7) * (nwg >> 3) + (id >> 3);
  const int bm = (swz / gx) * 128, bn = (swz % gx) * 128;

  const f32x4 fz = {0.f, 0.f, 0.f, 0.f};
  f32x4 acc[2][8];
#pragma unroll
  for (int a0 = 0; a0 < 2; ++a0)
#pragma unroll
    for (int b0 = 0; b0 < 8; ++b0) acc[a0][b0] = fz;

  for (int kt = 0; kt < K; kt += 64) {
    __syncthreads();
    if (ABF16) {
      const u16* A = (const u16*)Aptr;
#pragma unroll
      for (int p = 0; p < 4; ++p) {
        int row = p * 32 + (t >> 3), kc = (t & 7) * 8;
        *(s16x8*)&As[row][kc] = *(const s16x8*)(A + (size_t)(bm + row) * K + kt + kc);
      }
    } else {
      const float* A = (const float*)Aptr;
#pragma unroll
      for (int p = 0; p < 8; ++p) {
        int row = p * 16 + (t >> 4), kc = (t & 15) * 4;
        float4 f = *(const float4*)(A + (size_t)(bm + row) * K + kt + kc);
        unsigned* dst = (unsigned*)&As[row][kc];
        dst[0] = (unsigned)f2bf(f.x) | ((unsigned)f2bf(f.y) << 16);
        dst[1] = (unsigned)f2bf(f.z) | ((unsigned)f2bf(f.w) << 16);
      }
    }
    if (BBF16) {
      const u16* Bw = (const u16*)Bptr;
#pragma unroll
      for (int p = 0; p < 4; ++p) {
        int row = p * 32 + (t >> 3), kc = (t & 7) * 8;
        *(s16x8*)&Bs[row][kc] = *(const s16x8*)(Bw + (size_t)(bn + row) * K + kt + kc);
      }
    } else {
      const float* Bw = (const float*)Bptr;
#pragma unroll
      for (int p = 0; p < 8; ++p) {
        int row = p * 16 + (t >> 4), kc = (t & 15) * 4;
        float4 f = *(const float4*)(Bw + (size_t)(bn + row) * K + kt + kc);
        unsigned* dst = (unsigned*)&Bs[row][kc];
        dst[0] = (unsigned)f2bf(f.x) | ((unsigned)f2bf(f.y) << 16);
        dst[1] = (unsigned)f2bf(f.z) | ((unsigned)f2bf(f.w) << 16);
      }
    }
    __syncthreads();
#pragma unroll
    for (int ks = 0; ks < 2; ++ks) {
      s16x8 bfr[8];
#pragma unroll
      for (int nf = 0; nf < 8; ++nf)
        bfr[nf] = *(const s16x8*)&Bs[nf * 16 + l15][ks * 32 + lhi * 8];
#pragma unroll
      for (int mf = 0; mf < 2; ++mf) {
        s16x8 a = *(const s16x8*)&As[wave * 32 + mf * 16 + l15][ks * 32 + lhi * 8];
#pragma unroll
        for (int nf = 0; nf < 8; ++nf)
          acc[mf][nf] = __builtin_amdgcn_mfma_f32_16x16x32_bf16(a, bfr[nf], acc[mf][nf], 0, 0, 0);
      }
    }
  }

  // ---- epilogue ----
  if (EPI == 0) {
    float* C = (float*)outp;
#pragma unroll
    for (int mf = 0; mf < 2; ++mf)
#pragma unroll
      for (int nf = 0; nf < 8; ++nf) {
        int col = bn + nf * 16 + l15;
        int rb = bm + wave * 32 + mf * 16 + lhi * 4;
#pragma unroll
        for (int i = 0; i < 4; ++i) C[(size_t)(rb + i) * N + col] = acc[mf][nf][i];
      }
  } else if (EPI == 1) {
    u16* O = (u16*)outp;
#pragma unroll
    for (int mf = 0; mf < 2; ++mf)
#pragma unroll
      for (int nf = 0; nf < 8; ++nf) {
        int col = bn + nf * 16 + l15;
        int h = col >> 7, d = col & 127;
        int rb = bm + wave * 32 + mf * 16 + lhi * 4;
#pragma unroll
        for (int i = 0; i < 4; ++i) {
          int m = rb + i;
          int b = m >> 11, srow = m & 2047;
          O[((size_t)(b * Hh + h) * S_LEN + srow) * DHEAD + d] = f2bf(acc[mf][nf][i]);
        }
      }
  } else if (EPI == 2) {  // RoPE
    u16* O = (u16*)outp;
    int h = bn >> 7;
#pragma unroll
    for (int mf = 0; mf < 2; ++mf)
#pragma unroll
      for (int nf = 0; nf < 4; ++nf) {
        int j = nf * 16 + l15;
        int rb = bm + wave * 32 + mf * 16 + lhi * 4;
#pragma unroll
        for (int i = 0; i < 4; ++i) {
          int m = rb + i;
          int b = m >> 11, srow = m & 2047;
          float c = cos_t[srow * 64 + j];
          float s = sin_t[srow * 64 + j];
          float x0 = acc[mf][nf][i];
          float x1 = acc[mf][nf + 4][i];
          size_t base = ((size_t)(b * Hh + h) * S_LEN + srow) * DHEAD;
          O[base + j] = f2bf(x0 * c - x1 * s);
          O[base + j + 64] = f2bf(x0 * s + x1 * c);
        }
      }
  } else {  // EPI == 3: fused k (RoPE) | v (plain)
    if (bn < 1024) {
      u16* O = (u16*)outp;
      int h = bn >> 7;
#pragma unroll
      for (int mf = 0; mf < 2; ++mf)
#pragma unroll
        for (int nf = 0; nf < 4; ++nf) {
          int j = nf * 16 + l15;
          int rb = bm + wave * 32 + mf * 16 + lhi * 4;
#pragma unroll
          for (int i = 0; i < 4; ++i) {
            int m = rb + i;
            int b = m >> 11, srow = m & 2047;
            float c = cos_t[srow * 64 + j];
            float s = sin_t[srow * 64 + j];
            float x0 = acc[mf][nf][i];
            float x1 = acc[mf][nf + 4][i];
            size_t base = ((size_t)(b * NKV_H + h) * S_LEN + srow) * DHEAD;
            O[base + j] = f2bf(x0 * c - x1 * s);
            O[base + j + 64] = f2bf(x0 * s + x1 * c);
          }
        }
    } else {
      u16* O = (u16*)outp2;
#pragma unroll
      for (int mf = 0; mf < 2; ++mf)
#pragma unroll
        for (int nf = 0; nf < 8; ++nf) {
          int col = bn - 1024 + nf * 16 + l15;
          int h = col >> 7, d = col & 127;
          int rb = bm + wave * 32 + mf * 16 + lhi * 4;
#pragma unroll
          for (int i = 0; i < 4; ++i) {
            int m = rb + i;
            int b = m >> 11, srow = m & 2047;
            O[((size_t)(b * NKV_H + h) * S_LEN + srow) * DHEAD + d] = f2bf(acc[mf][nf][i]);
          }
        }
    }
  }
}

// ---------------- Flash attention (causal, GQA), swapped-QK in-register softmax ----
// grid: (S/128, NH, B); 8 waves x 16 q-rows; KV tile = 64; Q in registers.
// QK^T computed as mfma(K_frag, Q_frag) -> S[kv][q], q = lane&15: softmax per-lane.
__global__ __launch_bounds__(512) void attn_kernel(
    const u16* __restrict__ q, const u16* __restrict__ k, const u16* __restrict__ v,
    u16* __restrict__ ctx) {
  __shared__ u16 Ks[64][136];   // K row-major [kv][d]
  __shared__ u16 Vts[128][72];  // V transposed [d][kv], kv-block XOR-swizzled

  const int t = threadIdx.x;
  const int wave = t >> 6, lane = t & 63;
  const int l15 = lane & 15, lhi = lane >> 4;
  const int qtile = gridDim.x - 1 - blockIdx.x;  // heavy blocks first
  const int h = blockIdx.y, b = blockIdx.z;
  const int kvh = h >> 2;

  const u16* qb = q + (((size_t)(b * NH_Q + h)) * S_LEN + qtile * 128) * DHEAD;
  const u16* kb = k + ((size_t)(b * NKV_H + kvh)) * S_LEN * DHEAD;
  const u16* vb = v + ((size_t)(b * NKV_H + kvh)) * S_LEN * DHEAD;

  // Q fragments (B-operand): lane l15 = q-row, k = ks*32 + lhi*8 + j
  s16x8 qf[4];
#pragma unroll
  for (int ks = 0; ks < 4; ++ks)
    qf[ks] = *(const s16x8*)(qb + (size_t)(wave * 16 + l15) * DHEAD + ks * 32 + lhi * 8);

  const f32x4 fz = {0.f, 0.f, 0.f, 0.f};
  f32x4 acc[8];
#pragma unroll
  for (int i = 0; i < 8; ++i) acc[i] = fz;
  float mrow = -INFINITY, lsum = 0.f;  // per-lane (q = l15)

  const float scale = 0.08838834764831845f;
  const int ntiles = qtile * 2 + 2;
  const int wrow_min = qtile * 128 + wave * 16;
  const int qg = wrow_min + l15;  // this lane's global q row

  // shfl sources for P-fragment assembly (static per lane)
  const int s0 = l15 | (((2 * lhi) & 3) << 4);
  const int s1 = s0 | 16;
  const bool hisel = (lhi & 2) != 0;

  const int srow = t >> 4, sd0 = (t & 15) * 8;
  s16x8 kreg[2], vreg[2];
#pragma unroll
  for (int p = 0; p < 2; ++p) {
    int row = p * 32 + srow;
    kreg[p] = *(const s16x8*)(kb + (size_t)row * DHEAD + sd0);
    vreg[p] = *(const s16x8*)(vb + (size_t)row * DHEAD + sd0);
  }

  for (int tt = 0; tt < ntiles; ++tt) {
    __syncthreads();
    {  // write staged K/V regs to LDS
      const int sw = (sd0 >> 3) & 7;
#pragma unroll
      for (int p = 0; p < 2; ++p) {
        int row = p * 32 + srow;
        *(s16x8*)&Ks[row][sd0] = kreg[p];
        int colb = (((row >> 3) ^ sw) << 3) + (row & 7);
#pragma unroll
        for (int j = 0; j < 8; ++j) Vts[sd0 + j][colb] = (u16)vreg[p][j];
      }
    }
    __syncthreads();
    if (tt + 1 < ntiles) {  // prefetch next tile (overlaps compute)
#pragma unroll
      for (int p = 0; p < 2; ++p) {
        int row = (tt + 1) * 64 + p * 32 + srow;
        kreg[p] = *(const s16x8*)(kb + (size_t)row * DHEAD + sd0);
        vreg[p] = *(const s16x8*)(vb + (size_t)row * DHEAD + sd0);
      }
    }

    const int kc_base = tt * 64;
    if (kc_base <= wrow_min + 15) {
      // ---- S^T = K Q^T : sacc[nf][i] = S[kv = nf*16+lhi*4+i][q = l15] ----
      f32x4 sacc[4];
#pragma unroll
      for (int i = 0; i < 4; ++i) sacc[i] = fz;
      __builtin_amdgcn_s_setprio(1);
#pragma unroll
      for (int ks = 0; ks < 4; ++ks) {
#pragma unroll
        for (int nf = 0; nf < 4; ++nf) {
          s16x8 kf = *(const s16x8*)&Ks[nf * 16 + l15][ks * 32 + lhi * 8];
          sacc[nf] = __builtin_amdgcn_mfma_f32_16x16x32_bf16(kf, qf[ks], sacc[nf], 0, 0, 0);
        }
      }
      __builtin_amdgcn_s_setprio(0);

      // ---- scale + causal mask + per-lane online softmax ----
      float pmax = -INFINITY;
      if (kc_base + 63 > wrow_min) {  // diagonal tile
#pragma unroll
        for (int nf = 0; nf < 4; ++nf)
#pragma unroll
          for (int i = 0; i < 4; ++i) {
            int kv = kc_base + nf * 16 + lhi * 4 + i;
            float sv = sacc[nf][i] * scale;
            sv = (kv <= qg) ? sv : -INFINITY;
            sacc[nf][i] = sv;
            pmax = fmaxf(pmax, sv);
          }
      } else {
#pragma unroll
        for (int nf = 0; nf < 4; ++nf)
#pragma unroll
          for (int i = 0; i < 4; ++i) {
            float sv = sacc[nf][i] * scale;
            sacc[nf][i] = sv;
            pmax = fmaxf(pmax, sv);
          }
      }
      pmax = fmaxf(pmax, __shfl_xor(pmax, 16, 64));
      pmax = fmaxf(pmax, __shfl_xor(pmax, 32, 64));

      // defer-max (T13): rescale only when max grew past threshold
      if (!__all(pmax <= mrow + 8.0f)) {
        float mnew = fmaxf(mrow, pmax);
        float alpha = __expf(mrow - mnew);
        mrow = mnew;
        lsum *= alpha;
#pragma unroll
        for (int i = 0; i < 4; ++i) {
          float al = __shfl(alpha, (lane & 48) | (lhi * 4 + i), 64);
#pragma unroll
          for (int df = 0; df < 8; ++df) acc[df][i] *= al;
        }
      }

      // ---- P = exp(S - m), pack to bf16 pairs, accumulate row-sum ----
      float rsum = 0.f;
      unsigned pk[4][2];
#pragma unroll
      for (int nf = 0; nf < 4; ++nf) {
        float p0 = __expf(sacc[nf][0] - mrow);
        float p1 = __expf(sacc[nf][1] - mrow);
        float p2 = __expf(sacc[nf][2] - mrow);
        float p3 = __expf(sacc[nf][3] - mrow);
        rsum += (p0 + p1) + (p2 + p3);
        pk[nf][0] = (unsigned)f2bf(p0) | ((unsigned)f2bf(p1) << 16);
        pk[nf][1] = (unsigned)f2bf(p2) | ((unsigned)f2bf(p3) << 16);
      }
      rsum += __shfl_xor(rsum, 16, 64);
      rsum += __shfl_xor(rsum, 32, 64);
      lsum += rsum;

      // ---- assemble PV A-frags in-register via bpermute ----
      // pa[ph] elem j = P[q=l15][kv = ph*32 + lhi*8 + j]
      s16x8 pa[2];
#pragma unroll
      for (int ph = 0; ph < 2; ++ph) {
        unsigned lo0 = __shfl((int)pk[2 * ph][0], s0, 64);
        unsigned hi0 = __shfl((int)pk[2 * ph + 1][0], s0, 64);
        unsigned lo1 = __shfl((int)pk[2 * ph][1], s0, 64);
        unsigned hi1 = __shfl((int)pk[2 * ph + 1][1], s0, 64);
        unsigned lo2 = __shfl((int)pk[2 * ph][0], s1, 64);
        unsigned hi2 = __shfl((int)pk[2 * ph + 1][0], s1, 64);
        unsigned lo3 = __shfl((int)pk[2 * ph][1], s1, 64);
        unsigned hi3 = __shfl((int)pk[2 * ph + 1][1], s1, 64);
        u32x4 w;
        w[0] = hisel ? hi0 : lo0;
        w[1] = hisel ? hi1 : lo1;
        w[2] = hisel ? hi2 : lo2;
        w[3] = hisel ? hi3 : lo3;
        pa[ph] = __builtin_bit_cast(s16x8, w);
      }

      // ---- ctx += P V ----
      __builtin_amdgcn_s_setprio(1);
#pragma unroll
      for (int ph = 0; ph < 2; ++ph) {
#pragma unroll
        for (int df = 0; df < 8; ++df) {
          int d = df * 16 + l15;
          s16x8 bb = *(const s16x8*)&Vts[d][(((ph * 4 + lhi) ^ ((d >> 3) & 7)) << 3)];
          acc[df] = __builtin_amdgcn_mfma_f32_16x16x32_bf16(pa[ph], bb, acc[df], 0, 0, 0);
        }
      }
      __builtin_amdgcn_s_setprio(0);
    }
  }

  // ---- epilogue: ctx[b][s][h*128+d] bf16 ----
  float rl = 1.0f / lsum;  // per-lane q = l15
#pragma unroll
  for (int i = 0; i < 4; ++i) {
    float rli = __shfl(rl, (lane & 48) | (lhi * 4 + i), 64);
    int m = b * S_LEN + qtile * 128 + wave * 16 + lhi * 4 + i;
#pragma unroll
    for (int df = 0; df < 8; ++df) {
      int col = h * DHEAD + df * 16 + l15;
      ctx[(size_t)m * (NH_Q * DHEAD) + col] = f2bf(acc[df][i] * rli);
    }
  }
}

extern "C" void kernel_launch(void* const* d_in, const int* in_sizes, int n_in,
                              void* d_out, int out_size, void* d_ws, size_t ws_size,
                              hipStream_t stream) {
  const float* x = (const float*)d_in[0];
  const int* positions = (const int*)d_in[1];
  const float* wq = (const float*)d_in[2];
  const float* wk = (const float*)d_in[3];
  const float* wv = (const float*)d_in[4];
  const float* wo = (const float*)d_in[5];
  float* out = (float*)d_out;

  char* ws = (char*)d_ws;
  const size_t MB1 = 1048576;
  const size_t SZ_X = 33554432;    // 2*2048*4096 bf16
  const size_t SZ_WQ = 33554432;   // 4096*4096 bf16
  const size_t SZ_WK = 8388608;    // 1024*4096 bf16
  const size_t NEED_FULL = MB1 + SZ_X + SZ_WQ + 2 * SZ_WK + SZ_WQ + 2 * SZ_WK;

  float* cos_t = (float*)ws;
  float* sin_t = (float*)(ws + MB1 / 2);

  rope_table_kernel<<<512, 256, 0, stream>>>(positions, cos_t, sin_t);

  if (ws_size >= NEED_FULL) {
    char* p = ws + MB1;
    u16* x_bf = (u16*)p;   p += SZ_X;   // later reused as ctx
    u16* w_bf = (u16*)p;   p += SZ_WQ;  // wq first, wo later
    u16* wkv_bf = (u16*)p; p += 2 * SZ_WK;  // wk | wv contiguous (2048 x 4096)
    u16* q_ws = (u16*)p;   p += SZ_WQ;
    u16* k_ws = (u16*)p;   p += SZ_WK;
    u16* v_ws = (u16*)p;   p += SZ_WK;
    u16* ctx_ws = x_bf;

    cvt_kernel<<<2048, 256, 0, stream>>>(x, x_bf, 16777216 / 4);
    cvt_kernel<<<2048, 256, 0, stream>>>(wq, w_bf, 16777216 / 4);
    cvt_kernel<<<1024, 256, 0, stream>>>(wk, wkv_bf, 4194304 / 4);
    cvt_kernel<<<1024, 256, 0, stream>>>(wv, wkv_bf + 4194304, 4194304 / 4);

    gemm_kernel<2, true, true><<<dim3(32, 32), 256, 0, stream>>>(
        x_bf, w_bf, q_ws, nullptr, 4096, 4096, 4096, cos_t, sin_t, NH_Q);
    cvt_kernel<<<2048, 256, 0, stream>>>(wo, w_bf, 16777216 / 4);  // w_bf now = wo_bf
    gemm_kernel<3, true, true><<<dim3(16, 32), 256, 0, stream>>>(
        x_bf, wkv_bf, k_ws, v_ws, 4096, 2048, 4096, cos_t, sin_t, NKV_H);
    attn_kernel<<<dim3(16, 32, 2), 512, 0, stream>>>(q_ws, k_ws, v_ws, ctx_ws);
    gemm_kernel<0, true, true><<<dim3(32, 32), 256, 0, stream>>>(
        ctx_ws, w_bf, out, nullptr, 4096, 4096, 4096, nullptr, nullptr, 0);
  } else {
    u16* q_ws = (u16*)(ws + MB1);
    u16* k_ws = (u16*)(ws + MB1 + SZ_WQ);
    u16* v_ws = (u16*)(ws + MB1 + SZ_WQ + SZ_WK);
    u16* ctx_ws = (u16*)(ws + MB1 + SZ_WQ + 2 * SZ_WK);

    gemm_kernel<2, false, false><<<dim3(32, 32), 256, 0, stream>>>(
        x, wq, q_ws, nullptr, 4096, 4096, 4096, cos_t, sin_t, NH_Q);
    gemm_kernel<2, false, false><<<dim3(8, 32), 256, 0, stream>>>(
        x, wk, k_ws, nullptr, 4096, 1024, 4096, cos_t, sin_t, NKV_H);
    gemm_kernel<1, false, false><<<dim3(8, 32), 256, 0, stream>>>(
        x, wv, v_ws, nullptr, 4096, 1024, 4096, nullptr, nullptr, NKV_H);
    attn_kernel<<<dim3(16, 32, 2), 512, 0, stream>>>(q_ws, k_ws, v_ws, ctx_ws);
    gemm_kernel<0, true, false><<<dim3(32, 32), 256, 0, stream>>>(
        ctx_ws, wo, out, nullptr, 4096, 4096, 4096, nullptr, nullptr, 0);
  }
}

// Round 4
// 660.448 us; speedup vs baseline: 2.7460x; 1.1992x over previous
//
#include <hip/hip_runtime.h>
#include <math.h>

typedef short s16x8 __attribute__((ext_vector_type(8)));
typedef float f32x4 __attribute__((ext_vector_type(4)));
typedef unsigned u32x4 __attribute__((ext_vector_type(4)));
typedef unsigned short u16;

#define S_LEN 2048
#define HID_DIM 4096
#define NH_Q 32
#define NKV_H 8
#define DHEAD 128

__device__ __forceinline__ u16 f2bf(float f) {
  unsigned u = __builtin_bit_cast(unsigned, f);
  u += 0x7fffu + ((u >> 16) & 1u);
  return (u16)(u >> 16);
}

// ---------------- f32 -> bf16 bulk convert ----------------
__global__ void cvt_kernel(const float* __restrict__ in, u16* __restrict__ out, int n4) {
  int stride = gridDim.x * blockDim.x;
  for (int i = blockIdx.x * blockDim.x + threadIdx.x; i < n4; i += stride) {
    float4 f = ((const float4*)in)[i];
    uint2 o;
    o.x = (unsigned)f2bf(f.x) | ((unsigned)f2bf(f.y) << 16);
    o.y = (unsigned)f2bf(f.z) | ((unsigned)f2bf(f.w) << 16);
    ((uint2*)out)[i] = o;
  }
}

// ---------------- RoPE tables: cos/sin [S][64] ----------------
__global__ void rope_table_kernel(const int* __restrict__ positions,
                                  float* __restrict__ cos_t, float* __restrict__ sin_t) {
  int idx = blockIdx.x * 256 + threadIdx.x;
  if (idx >= S_LEN * 64) return;
  int s = idx >> 6, j = idx & 63;
  float pos = (float)positions[s];
  float inv = expf(-(float)j * (9.210340371976184f / 64.0f));
  float ang = pos * inv;
  float sv, cv;
  sincosf(ang, &sv, &cv);
  cos_t[idx] = cv;
  sin_t[idx] = sv;
}

// ---------------- GEMM: C[M][N] = A[M][K] * B[N][K]^T, BK=64 ----------------
// EPI: 0 = f32 row-major out; 1 = bf16 out to [b][h][s][d]; 2 = RoPE + bf16 out;
//      3 = fused kv: cols [0,1024) RoPE->outp (k, [b][h][s][d]),
//                    cols [1024,2048) plain->outp2 (v TRANSPOSED: [b][h][d][s]);
//      4 = bf16 out transposed [b][h][d][s]
template<int EPI, bool ABF16, bool BBF16>
__global__ __launch_bounds__(256) void gemm_kernel(
    const void* __restrict__ Aptr, const void* __restrict__ Bptr,
    void* __restrict__ outp, void* __restrict__ outp2, int M, int N, int K,
    const float* __restrict__ cos_t, const float* __restrict__ sin_t, int Hh) {
  __shared__ u16 As[128][72];  // 128 x 64 bf16, stride 144B
  __shared__ u16 Bs[128][72];
  const int t = threadIdx.x;
  const int wave = t >> 6, lane = t & 63;
  const int l15 = lane & 15, lhi = lane >> 4;
  // bijective XCD swizzle (all our grids are multiples of 8)
  const int gx = gridDim.x;
  const int nwg = gx * gridDim.y;
  const int id = blockIdx.y * gx + blockIdx.x;
  const int swz = (id & 7) * (nwg >> 3) + (id >> 3);
  const int bm = (swz / gx) * 128, bn = (swz % gx) * 128;

  const f32x4 fz = {0.f, 0.f, 0.f, 0.f};
  f32x4 acc[2][8];
#pragma unroll
  for (int a0 = 0; a0 < 2; ++a0)
#pragma unroll
    for (int b0 = 0; b0 < 8; ++b0) acc[a0][b0] = fz;

  for (int kt = 0; kt < K; kt += 64) {
    __syncthreads();
    if (ABF16) {
      const u16* A = (const u16*)Aptr;
#pragma unroll
      for (int p = 0; p < 4; ++p) {
        int row = p * 32 + (t >> 3), kc = (t & 7) * 8;
        *(s16x8*)&As[row][kc] = *(const s16x8*)(A + (size_t)(bm + row) * K + kt + kc);
      }
    } else {
      const float* A = (const float*)Aptr;
#pragma unroll
      for (int p = 0; p < 8; ++p) {
        int row = p * 16 + (t >> 4), kc = (t & 15) * 4;
        float4 f = *(const float4*)(A + (size_t)(bm + row) * K + kt + kc);
        unsigned* dst = (unsigned*)&As[row][kc];
        dst[0] = (unsigned)f2bf(f.x) | ((unsigned)f2bf(f.y) << 16);
        dst[1] = (unsigned)f2bf(f.z) | ((unsigned)f2bf(f.w) << 16);
      }
    }
    if (BBF16) {
      const u16* Bw = (const u16*)Bptr;
#pragma unroll
      for (int p = 0; p < 4; ++p) {
        int row = p * 32 + (t >> 3), kc = (t & 7) * 8;
        *(s16x8*)&Bs[row][kc] = *(const s16x8*)(Bw + (size_t)(bn + row) * K + kt + kc);
      }
    } else {
      const float* Bw = (const float*)Bptr;
#pragma unroll
      for (int p = 0; p < 8; ++p) {
        int row = p * 16 + (t >> 4), kc = (t & 15) * 4;
        float4 f = *(const float4*)(Bw + (size_t)(bn + row) * K + kt + kc);
        unsigned* dst = (unsigned*)&Bs[row][kc];
        dst[0] = (unsigned)f2bf(f.x) | ((unsigned)f2bf(f.y) << 16);
        dst[1] = (unsigned)f2bf(f.z) | ((unsigned)f2bf(f.w) << 16);
      }
    }
    __syncthreads();
#pragma unroll
    for (int ks = 0; ks < 2; ++ks) {
      s16x8 bfr[8];
#pragma unroll
      for (int nf = 0; nf < 8; ++nf)
        bfr[nf] = *(const s16x8*)&Bs[nf * 16 + l15][ks * 32 + lhi * 8];
#pragma unroll
      for (int mf = 0; mf < 2; ++mf) {
        s16x8 a = *(const s16x8*)&As[wave * 32 + mf * 16 + l15][ks * 32 + lhi * 8];
#pragma unroll
        for (int nf = 0; nf < 8; ++nf)
          acc[mf][nf] = __builtin_amdgcn_mfma_f32_16x16x32_bf16(a, bfr[nf], acc[mf][nf], 0, 0, 0);
      }
    }
  }

  // ---- epilogue ----
  if (EPI == 0) {
    float* C = (float*)outp;
#pragma unroll
    for (int mf = 0; mf < 2; ++mf)
#pragma unroll
      for (int nf = 0; nf < 8; ++nf) {
        int col = bn + nf * 16 + l15;
        int rb = bm + wave * 32 + mf * 16 + lhi * 4;
#pragma unroll
        for (int i = 0; i < 4; ++i) C[(size_t)(rb + i) * N + col] = acc[mf][nf][i];
      }
  } else if (EPI == 1) {
    u16* O = (u16*)outp;
#pragma unroll
    for (int mf = 0; mf < 2; ++mf)
#pragma unroll
      for (int nf = 0; nf < 8; ++nf) {
        int col = bn + nf * 16 + l15;
        int h = col >> 7, d = col & 127;
        int rb = bm + wave * 32 + mf * 16 + lhi * 4;
#pragma unroll
        for (int i = 0; i < 4; ++i) {
          int m = rb + i;
          int b = m >> 11, srow = m & 2047;
          O[((size_t)(b * Hh + h) * S_LEN + srow) * DHEAD + d] = f2bf(acc[mf][nf][i]);
        }
      }
  } else if (EPI == 2) {  // RoPE
    u16* O = (u16*)outp;
    int h = bn >> 7;
#pragma unroll
    for (int mf = 0; mf < 2; ++mf)
#pragma unroll
      for (int nf = 0; nf < 4; ++nf) {
        int j = nf * 16 + l15;
        int rb = bm + wave * 32 + mf * 16 + lhi * 4;
#pragma unroll
        for (int i = 0; i < 4; ++i) {
          int m = rb + i;
          int b = m >> 11, srow = m & 2047;
          float c = cos_t[srow * 64 + j];
          float s = sin_t[srow * 64 + j];
          float x0 = acc[mf][nf][i];
          float x1 = acc[mf][nf + 4][i];
          size_t base = ((size_t)(b * Hh + h) * S_LEN + srow) * DHEAD;
          O[base + j] = f2bf(x0 * c - x1 * s);
          O[base + j + 64] = f2bf(x0 * s + x1 * c);
        }
      }
  } else if (EPI == 3) {  // fused k (RoPE, [b][h][s][d]) | v (plain, transposed [b][h][d][s])
    if (bn < 1024) {
      u16* O = (u16*)outp;
      int h = bn >> 7;
#pragma unroll
      for (int mf = 0; mf < 2; ++mf)
#pragma unroll
        for (int nf = 0; nf < 4; ++nf) {
          int j = nf * 16 + l15;
          int rb = bm + wave * 32 + mf * 16 + lhi * 4;
#pragma unroll
          for (int i = 0; i < 4; ++i) {
            int m = rb + i;
            int b = m >> 11, srow = m & 2047;
            float c = cos_t[srow * 64 + j];
            float s = sin_t[srow * 64 + j];
            float x0 = acc[mf][nf][i];
            float x1 = acc[mf][nf + 4][i];
            size_t base = ((size_t)(b * NKV_H + h) * S_LEN + srow) * DHEAD;
            O[base + j] = f2bf(x0 * c - x1 * s);
            O[base + j + 64] = f2bf(x0 * s + x1 * c);
          }
        }
    } else {
      u16* O = (u16*)outp2;
#pragma unroll
      for (int mf = 0; mf < 2; ++mf)
#pragma unroll
        for (int nf = 0; nf < 8; ++nf) {
          int col = bn - 1024 + nf * 16 + l15;
          int h = col >> 7, d = col & 127;
          int rb = bm + wave * 32 + mf * 16 + lhi * 4;
#pragma unroll
          for (int i = 0; i < 4; ++i) {
            int m = rb + i;
            int b = m >> 11, srow = m & 2047;
            O[((size_t)(b * NKV_H + h) * DHEAD + d) * S_LEN + srow] = f2bf(acc[mf][nf][i]);
          }
        }
    }
  } else {  // EPI == 4: bf16 transposed [b][h][d][s]
    u16* O = (u16*)outp;
#pragma unroll
    for (int mf = 0; mf < 2; ++mf)
#pragma unroll
      for (int nf = 0; nf < 8; ++nf) {
        int col = bn + nf * 16 + l15;
        int h = col >> 7, d = col & 127;
        int rb = bm + wave * 32 + mf * 16 + lhi * 4;
#pragma unroll
        for (int i = 0; i < 4; ++i) {
          int m = rb + i;
          int b = m >> 11, srow = m & 2047;
          O[((size_t)(b * Hh + h) * DHEAD + d) * S_LEN + srow] = f2bf(acc[mf][nf][i]);
        }
      }
  }
}

// ---------------- Flash attention (causal, GQA) ----------------
// Paired q-tiles for perfect balance: block = pair (pi, 15-pi), each of 128 rows.
// grid: (8, NH, B) x 512 thr. 8 waves; wave owns 16 rows of EACH sub-tile.
// Swapped QK^T (softmax per-lane), V pre-transposed in global, XOR-swizzled LDS.
#define KIDX(r, c) (((r) * 128 + (c)) ^ (((r) & 7) << 3))
#define VIDX(d, kv) (((d) * 64 + (kv)) ^ (((d) & 7) << 3))
__global__ __launch_bounds__(512) void attn_kernel(
    const u16* __restrict__ q, const u16* __restrict__ k, const u16* __restrict__ vt,
    u16* __restrict__ ctx) {
  __shared__ u16 Ks[64 * 128];   // K [kv][d], XOR-swizzled
  __shared__ u16 Vts[128 * 64];  // V^T [d][kv], XOR-swizzled

  const int t = threadIdx.x;
  const int wave = t >> 6, lane = t & 63;
  const int l15 = lane & 15, lhi = lane >> 4;
  const int pi = blockIdx.x, h = blockIdx.y, b = blockIdx.z;
  const int kvh = h >> 2;
  const int qsub[2] = {pi, 15 - pi};
  const int ntiles = 32 - 2 * pi;  // range of the larger sub-tile

  const u16* qb = q + ((size_t)(b * NH_Q + h)) * S_LEN * DHEAD;
  const u16* kb = k + ((size_t)(b * NKV_H + kvh)) * S_LEN * DHEAD;
  const u16* vtb = vt + ((size_t)(b * NKV_H + kvh)) * DHEAD * S_LEN;

  // Q fragments for both sub-tiles (B-operand: lane l15 = q-row)
  s16x8 qf[2][4];
#pragma unroll
  for (int s = 0; s < 2; ++s)
#pragma unroll
    for (int ks = 0; ks < 4; ++ks)
      qf[s][ks] = *(const s16x8*)(qb + (size_t)(qsub[s] * 128 + wave * 16 + l15) * DHEAD +
                                  ks * 32 + lhi * 8);

  const f32x4 fz = {0.f, 0.f, 0.f, 0.f};
  f32x4 acc[2][8];
#pragma unroll
  for (int s = 0; s < 2; ++s)
#pragma unroll
    for (int i = 0; i < 8; ++i) acc[s][i] = fz;
  float mrow[2] = {-INFINITY, -INFINITY};
  float lsum[2] = {0.f, 0.f};

  const float scale = 0.08838834764831845f;

  // shfl sources for P-fragment assembly (static per lane)
  const int sl0 = l15 | (((2 * lhi) & 3) << 4);
  const int sl1 = sl0 | 16;
  const bool hisel = (lhi & 2) != 0;

  // staging mapping: K: thread -> (row kv, 16 d); V^T: thread -> (row d, 16 kv)
  const int krow = t >> 3, kd0 = (t & 7) * 16;
  const int vrow = t >> 2, vk0 = (t & 3) * 16;
  s16x8 kr0, kr1, vr0, vr1;
  {
    const u16* p = kb + (size_t)krow * DHEAD + kd0;
    kr0 = *(const s16x8*)p;
    kr1 = *(const s16x8*)(p + 8);
    const u16* pv = vtb + (size_t)vrow * S_LEN + vk0;
    vr0 = *(const s16x8*)pv;
    vr1 = *(const s16x8*)(pv + 8);
  }

  for (int tt = 0; tt < ntiles; ++tt) {
    __syncthreads();  // previous tile's readers done
    *(s16x8*)&Ks[KIDX(krow, kd0)] = kr0;
    *(s16x8*)&Ks[KIDX(krow, kd0 + 8)] = kr1;
    *(s16x8*)&Vts[VIDX(vrow, vk0)] = vr0;
    *(s16x8*)&Vts[VIDX(vrow, vk0 + 8)] = vr1;
    __syncthreads();
    if (tt + 1 < ntiles) {  // prefetch next tile (latency hidden by compute)
      const u16* p = kb + (size_t)((tt + 1) * 64 + krow) * DHEAD + kd0;
      kr0 = *(const s16x8*)p;
      kr1 = *(const s16x8*)(p + 8);
      const u16* pv = vtb + (size_t)vrow * S_LEN + (tt + 1) * 64 + vk0;
      vr0 = *(const s16x8*)pv;
      vr1 = *(const s16x8*)(pv + 8);
    }

    const int kc_base = tt * 64;
#pragma unroll
    for (int s = 0; s < 2; ++s) {
      const int wmin = qsub[s] * 128 + wave * 16;
      if (kc_base > wmin + 15) continue;  // fully masked for this wave
      // ---- S^T = K Q^T : sacc[nf][i] = S[kv = nf*16+lhi*4+i][q = l15] ----
      f32x4 sacc[4];
#pragma unroll
      for (int i = 0; i < 4; ++i) sacc[i] = fz;
      __builtin_amdgcn_s_setprio(1);
#pragma unroll
      for (int ks = 0; ks < 4; ++ks) {
#pragma unroll
        for (int nf = 0; nf < 4; ++nf) {
          s16x8 kf = *(const s16x8*)&Ks[KIDX(nf * 16 + l15, ks * 32 + lhi * 8)];
          sacc[nf] = __builtin_amdgcn_mfma_f32_16x16x32_bf16(kf, qf[s][ks], sacc[nf], 0, 0, 0);
        }
      }
      __builtin_amdgcn_s_setprio(0);

      // ---- scale + causal mask + per-lane online softmax ----
      const int qg = wmin + l15;
      float pmax = -INFINITY;
      if (kc_base + 63 > wmin) {  // diagonal tile
#pragma unroll
        for (int nf = 0; nf < 4; ++nf)
#pragma unroll
          for (int i = 0; i < 4; ++i) {
            int kv = kc_base + nf * 16 + lhi * 4 + i;
            float sv = sacc[nf][i] * scale;
            sv = (kv <= qg) ? sv : -INFINITY;
            sacc[nf][i] = sv;
            pmax = fmaxf(pmax, sv);
          }
      } else {
#pragma unroll
        for (int nf = 0; nf < 4; ++nf)
#pragma unroll
          for (int i = 0; i < 4; ++i) {
            float sv = sacc[nf][i] * scale;
            sacc[nf][i] = sv;
            pmax = fmaxf(pmax, sv);
          }
      }
      pmax = fmaxf(pmax, __shfl_xor(pmax, 16, 64));
      pmax = fmaxf(pmax, __shfl_xor(pmax, 32, 64));

      // defer-max (T13)
      if (!__all(pmax <= mrow[s] + 8.0f)) {
        float mnew = fmaxf(mrow[s], pmax);
        float alpha = __expf(mrow[s] - mnew);
        mrow[s] = mnew;
        lsum[s] *= alpha;
#pragma unroll
        for (int i = 0; i < 4; ++i) {
          float al = __shfl(alpha, (lane & 48) | (lhi * 4 + i), 64);
#pragma unroll
          for (int df = 0; df < 8; ++df) acc[s][df][i] *= al;
        }
      }

      // ---- P = exp(S - m), pack bf16 pairs, row-sum ----
      float rsum = 0.f;
      unsigned pk[4][2];
#pragma unroll
      for (int nf = 0; nf < 4; ++nf) {
        float p0 = __expf(sacc[nf][0] - mrow[s]);
        float p1 = __expf(sacc[nf][1] - mrow[s]);
        float p2 = __expf(sacc[nf][2] - mrow[s]);
        float p3 = __expf(sacc[nf][3] - mrow[s]);
        rsum += (p0 + p1) + (p2 + p3);
        pk[nf][0] = (unsigned)f2bf(p0) | ((unsigned)f2bf(p1) << 16);
        pk[nf][1] = (unsigned)f2bf(p2) | ((unsigned)f2bf(p3) << 16);
      }
      rsum += __shfl_xor(rsum, 16, 64);
      rsum += __shfl_xor(rsum, 32, 64);
      lsum[s] += rsum;

      // ---- assemble PV A-frags in-register ----
      s16x8 pa[2];
#pragma unroll
      for (int ph = 0; ph < 2; ++ph) {
        unsigned lo0 = __shfl((int)pk[2 * ph][0], sl0, 64);
        unsigned hi0 = __shfl((int)pk[2 * ph + 1][0], sl0, 64);
        unsigned lo1 = __shfl((int)pk[2 * ph][1], sl0, 64);
        unsigned hi1 = __shfl((int)pk[2 * ph + 1][1], sl0, 64);
        unsigned lo2 = __shfl((int)pk[2 * ph][0], sl1, 64);
        unsigned hi2 = __shfl((int)pk[2 * ph + 1][0], sl1, 64);
        unsigned lo3 = __shfl((int)pk[2 * ph][1], sl1, 64);
        unsigned hi3 = __shfl((int)pk[2 * ph + 1][1], sl1, 64);
        u32x4 w;
        w[0] = hisel ? hi0 : lo0;
        w[1] = hisel ? hi1 : lo1;
        w[2] = hisel ? hi2 : lo2;
        w[3] = hisel ? hi3 : lo3;
        pa[ph] = __builtin_bit_cast(s16x8, w);
      }

      // ---- ctx += P V ----
      __builtin_amdgcn_s_setprio(1);
#pragma unroll
      for (int ph = 0; ph < 2; ++ph) {
#pragma unroll
        for (int df = 0; df < 8; ++df) {
          s16x8 bb = *(const s16x8*)&Vts[VIDX(df * 16 + l15, ph * 32 + lhi * 8)];
          acc[s][df] = __builtin_amdgcn_mfma_f32_16x16x32_bf16(pa[ph], bb, acc[s][df], 0, 0, 0);
        }
      }
      __builtin_amdgcn_s_setprio(0);
    }
  }

  // ---- epilogue: ctx[b][s][h*128+d] bf16, both sub-tiles ----
#pragma unroll
  for (int s = 0; s < 2; ++s) {
    float rl = 1.0f / lsum[s];
#pragma unroll
    for (int i = 0; i < 4; ++i) {
      float rli = __shfl(rl, (lane & 48) | (lhi * 4 + i), 64);
      int m = b * S_LEN + qsub[s] * 128 + wave * 16 + lhi * 4 + i;
#pragma unroll
      for (int df = 0; df < 8; ++df) {
        int col = h * DHEAD + df * 16 + l15;
        ctx[(size_t)m * (NH_Q * DHEAD) + col] = f2bf(acc[s][df][i] * rli);
      }
    }
  }
}

extern "C" void kernel_launch(void* const* d_in, const int* in_sizes, int n_in,
                              void* d_out, int out_size, void* d_ws, size_t ws_size,
                              hipStream_t stream) {
  const float* x = (const float*)d_in[0];
  const int* positions = (const int*)d_in[1];
  const float* wq = (const float*)d_in[2];
  const float* wk = (const float*)d_in[3];
  const float* wv = (const float*)d_in[4];
  const float* wo = (const float*)d_in[5];
  float* out = (float*)d_out;

  char* ws = (char*)d_ws;
  const size_t MB1 = 1048576;
  const size_t SZ_X = 33554432;    // 2*2048*4096 bf16
  const size_t SZ_WQ = 33554432;   // 4096*4096 bf16
  const size_t SZ_WK = 8388608;    // 1024*4096 bf16
  const size_t NEED_FULL = MB1 + SZ_X + SZ_WQ + 2 * SZ_WK + SZ_WQ + 2 * SZ_WK;

  float* cos_t = (float*)ws;
  float* sin_t = (float*)(ws + MB1 / 2);

  rope_table_kernel<<<512, 256, 0, stream>>>(positions, cos_t, sin_t);

  if (ws_size >= NEED_FULL) {
    char* p = ws + MB1;
    u16* x_bf = (u16*)p;   p += SZ_X;       // later reused as ctx
    u16* w_bf = (u16*)p;   p += SZ_WQ;      // wq first, wo later
    u16* wkv_bf = (u16*)p; p += 2 * SZ_WK;  // wk | wv contiguous (2048 x 4096)
    u16* q_ws = (u16*)p;   p += SZ_WQ;
    u16* k_ws = (u16*)p;   p += SZ_WK;
    u16* v_ws = (u16*)p;   p += SZ_WK;      // V^T: [b][kvh][d][s]
    u16* ctx_ws = x_bf;

    cvt_kernel<<<2048, 256, 0, stream>>>(x, x_bf, 16777216 / 4);
    cvt_kernel<<<2048, 256, 0, stream>>>(wq, w_bf, 16777216 / 4);
    cvt_kernel<<<1024, 256, 0, stream>>>(wk, wkv_bf, 4194304 / 4);
    cvt_kernel<<<1024, 256, 0, stream>>>(wv, wkv_bf + 4194304, 4194304 / 4);

    gemm_kernel<2, true, true><<<dim3(32, 32), 256, 0, stream>>>(
        x_bf, w_bf, q_ws, nullptr, 4096, 4096, 4096, cos_t, sin_t, NH_Q);
    cvt_kernel<<<2048, 256, 0, stream>>>(wo, w_bf, 16777216 / 4);  // w_bf now = wo_bf
    gemm_kernel<3, true, true><<<dim3(16, 32), 256, 0, stream>>>(
        x_bf, wkv_bf, k_ws, v_ws, 4096, 2048, 4096, cos_t, sin_t, NKV_H);
    attn_kernel<<<dim3(8, 32, 2), 512, 0, stream>>>(q_ws, k_ws, v_ws, ctx_ws);
    gemm_kernel<0, true, true><<<dim3(32, 32), 256, 0, stream>>>(
        ctx_ws, w_bf, out, nullptr, 4096, 4096, 4096, nullptr, nullptr, 0);
  } else {
    u16* q_ws = (u16*)(ws + MB1);
    u16* k_ws = (u16*)(ws + MB1 + SZ_WQ);
    u16* v_ws = (u16*)(ws + MB1 + SZ_WQ + SZ_WK);
    u16* ctx_ws = (u16*)(ws + MB1 + SZ_WQ + 2 * SZ_WK);

    gemm_kernel<2, false, false><<<dim3(32, 32), 256, 0, stream>>>(
        x, wq, q_ws, nullptr, 4096, 4096, 4096, cos_t, sin_t, NH_Q);
    gemm_kernel<2, false, false><<<dim3(8, 32), 256, 0, stream>>>(
        x, wk, k_ws, nullptr, 4096, 1024, 4096, cos_t, sin_t, NKV_H);
    gemm_kernel<4, false, false><<<dim3(8, 32), 256, 0, stream>>>(
        x, wv, v_ws, nullptr, 4096, 1024, 4096, nullptr, nullptr, NKV_H);
    attn_kernel<<<dim3(8, 32, 2), 512, 0, stream>>>(q_ws, k_ws, v_ws, ctx_ws);
    gemm_kernel<0, true, false><<<dim3(32, 32), 256, 0, stream>>>(
        ctx_ws, wo, out, nullptr, 4096, 4096, 4096, nullptr, nullptr, 0);
  }
}